// Round 6
// baseline (5768.529 us; speedup 1.0000x reference)
//
#include <hip/hip_runtime.h>
#include <math.h>

#define HDIM 128
#define NSTEP 606
#define NW 8                    // waves per block
#define DSTR 129                // dpl row stride (floats)

// dynamic-LDS carve (float indices)
#define O_DPL   0                          // 122*129 = 15738
#define O_W5    15740                      // 24*52 = 1248 (16B aligned)
#define O_W6    (O_W5 + 24*52)             // 12*32 = 384
#define O_T0    (O_W6 + 12*32)             // NW*192
#define O_TA    (O_T0 + NW*192)            // NW*192
#define O_HIST  (O_TA + NW*192)            // 256 u32
#define O_WRED  (O_HIST + 256)             // NW
#define DYN_FLOATS (O_WRED + NW)
#define DYN_BYTES  (DYN_FLOATS * 4)        // ~82.8 KB

template <int CTRL>
__device__ __forceinline__ float dpp_qp(float v) {
  // quad_perm DPP move (VALU pipe, no LDS)
  return __int_as_float(__builtin_amdgcn_mov_dpp(__float_as_int(v), CTRL, 0xf, 0xf, true));
}
__device__ __forceinline__ float quad_red(float v) {
  v += dpp_qp<0xB1>(v);   // quad_perm [1,0,3,2]  (xor 1)
  v += dpp_qp<0x4E>(v);   // quad_perm [2,3,0,1]  (xor 2)
  return v;
}
__device__ __forceinline__ float sel4f(float a0, float a1, float a2, float a3, int lane) {
  float m01 = (lane & 1) ? a1 : a0;
  float m23 = (lane & 1) ? a3 : a2;
  return (lane & 2) ? m23 : m01;
}
__device__ __forceinline__ int sel4i(int a0, int a1, int a2, int a3, int lane) {
  int m01 = (lane & 1) ? a1 : a0;
  int m23 = (lane & 1) ? a3 : a2;
  return (lane & 2) ? m23 : m01;
}

__global__ __launch_bounds__(512, 1)
void codec_main_kernel(const float* __restrict__ x,
    const float* __restrict__ W1, const float* __restrict__ b1,
    const float* __restrict__ W2, const float* __restrict__ b2,
    const float* __restrict__ W3, const float* __restrict__ b3,
    const float* __restrict__ W4, const float* __restrict__ b4,
    const float* __restrict__ W5, const float* __restrict__ b5,
    const float* __restrict__ W6, const float* __restrict__ b6,
    const float* __restrict__ W7, const float* __restrict__ b7,
    unsigned* __restrict__ g_hist, float* __restrict__ g_sumsq)
{
  extern __shared__ float dyn[];
  float* dpl  = dyn + O_DPL;
  float* W5r  = dyn + O_W5;                 // [24][52]
  float* W6r  = dyn + O_W6;                 // [12][32], quarter q at col 8q
  unsigned* hist = (unsigned*)(dyn + O_HIST);
  float* wred = dyn + O_WRED;

  const int tid = threadIdx.x, wid = tid >> 6, lane = tid & 63;
  const int plane = blockIdx.x;
  const float* xp = x + (size_t)plane * (HDIM * HDIM);
  float* t0b = dyn + O_T0 + wid * 192;      // [48][4] px-packed, wave-private
  float* tab = dyn + O_TA + wid * 192;

  // ---- stage LDS weights, zero dpl/tbuf/hist/wred ----
  for (int i = tid; i < 24 * 48; i += 512) W5r[(i / 48) * 52 + (i % 48)] = W5[i];
  for (int i = tid; i < 12 * 24; i += 512) {
    int r = i / 24, k = i % 24;
    W6r[r * 32 + (k / 6) * 8 + (k % 6)] = W6[i];
  }
  for (int i = tid; i < 122 * DSTR; i += 512) dpl[i] = 0.f;
  for (int i = tid; i < NW * 384; i += 512) dyn[O_T0 + i] = 0.f;
  if (tid < 256) hist[tid] = 0u;
  if (tid < NW) wred[tid] = 0.f;

  // ---- per-lane register weights (L1-4); needs >128 VGPRs (launch_bounds 512,1) ----
  const int lt = lane >> 2, q = lane & 3;
  float w14[4][3][12], b14[4][3];
  {
    const float* Ws[4] = {W1, W2, W3, W4};
    const float* Bs[4] = {b1, b2, b3, b4};
    #pragma unroll
    for (int L = 0; L < 4; ++L)
      #pragma unroll
      for (int rr = 0; rr < 3; ++rr) {
        const int row = lt + 16 * rr;
        b14[L][rr] = Bs[L][row];
        #pragma unroll
        for (int kk = 0; kk < 12; ++kk) w14[L][rr][kk] = Ws[L][row * 48 + 12 * q + kk];
      }
  }
  const int lt5 = lt & 7, lt6 = lt & 3;
  float b5r[3], b6r[3], w7r[3];
  #pragma unroll
  for (int rr = 0; rr < 3; ++rr) {
    b5r[rr] = b5[lt5 + 8 * rr];
    b6r[rr] = b6[lt6 + 4 * rr];
    w7r[rr] = (lane < 16) ? W7[lt6 + 4 * rr] : 0.f;
  }
  const float B7v = b7[0];

  // ---- per-lane gather geometry ----
  const bool isx = (lane < 24) || (lane == 48);
  const bool isd = (lane >= 24 && lane < 48);
  int xro = 0, xco = 0, dro = 0, dco = 0;
  if (isx) { xro = (lane < 21) ? lane / 7 : 3; xco = (lane < 21) ? lane % 7 : (lane < 24 ? lane - 21 : 3); }
  if (isd) { const int g = lane - 24; dro = (g < 21) ? g / 7 - 3 : 0; dco = (g < 21) ? g % 7 : g - 21; }

  __syncthreads();

  float xpre[4] = {0.f, 0.f, 0.f, 0.f};
  float sumsq = 0.f;
  // initial prefetch for T=0
  #pragma unroll
  for (int p = 0; p < 4; ++p) {
    const int r = (wid & 7) + 8 * p, j = 0 - 4 * r;
    if (isx && j >= 0 && r <= 121) xpre[p] = xp[(r + xro) * HDIM + (j + xco)];
  }

  for (int T = 0; T < NSTEP; ++T) {
    const int r_lo = (T > 121) ? ((T - 118) >> 2) : 0;
    const int rbase = r_lo + ((wid - r_lo) & 7);

    int rs[4], js[4];
    bool act[4];
    float xcv[4] = {0.f, 0.f, 0.f, 0.f};
    #pragma unroll
    for (int p = 0; p < 4; ++p) {
      rs[p] = rbase + 8 * p;
      js[p] = T - 4 * rs[p];
      act[p] = (js[p] >= 0) && (rs[p] <= 121);
    }

    if (act[0]) {     // wave-uniform: any work this step?
      // ---- gather t0 (px-packed), grab xc ----
      #pragma unroll
      for (int p = 0; p < 4; ++p) {
        if (act[p]) {
          float v;
          if (isx) v = xpre[p];
          else if (isd) {
            const int drow = rs[p] + dro, dcol = js[p] + dco;
            v = (drow >= 0) ? dpl[drow * DSTR + dcol] : 0.f;
          } else v = 0.f;
          if (lane < 48) t0b[lane * 4 + p] = v;
          xcv[p] = __shfl(v, 48);
        }
      }
      // ---- prefetch x for T+1 (latency hidden under MLP) ----
      {
        const int Tn = T + 1;
        const int r_lo_n = (Tn > 121) ? ((Tn - 118) >> 2) : 0;
        const int rbase_n = r_lo_n + ((wid - r_lo_n) & 7);
        #pragma unroll
        for (int p = 0; p < 4; ++p) {
          const int rn = rbase_n + 8 * p, jn = Tn - 4 * rn;
          if (isx && jn >= 0 && rn <= 121) xpre[p] = xp[(rn + xro) * HDIM + (jn + xco)];
        }
      }

      // ---- L1-4: reg-weights, px-packed LDS activations, quad-reduce ----
      {
        const float* srcs[4] = {t0b, tab, tab, tab};
        #pragma unroll
        for (int L = 0; L < 4; ++L) {
          const float* src = srcs[L];
          float acc[3][4];
          #pragma unroll
          for (int rr = 0; rr < 3; ++rr)
            #pragma unroll
            for (int px = 0; px < 4; ++px) acc[rr][px] = 0.f;
          #pragma unroll
          for (int i = 0; i < 12; ++i) {
            const float4 tv = *(const float4*)(src + (12 * q + i) * 4);
            #pragma unroll
            for (int rr = 0; rr < 3; ++rr) {
              const float wv = w14[L][rr][i];
              acc[rr][0] += wv * tv.x; acc[rr][1] += wv * tv.y;
              acc[rr][2] += wv * tv.z; acc[rr][3] += wv * tv.w;
            }
          }
          #pragma unroll
          for (int rr = 0; rr < 3; ++rr) {
            const float s0 = quad_red(acc[rr][0]), s1 = quad_red(acc[rr][1]);
            const float s2 = quad_red(acc[rr][2]), s3 = quad_red(acc[rr][3]);
            float z = sel4f(s0, s1, s2, s3, q) + b14[L][rr];
            float o = (z >= 0.f) ? z : 0.01f * z;
            if (L == 3) o += t0b[(lt + 16 * rr) * 4 + q];
            tab[(lt + 16 * rr) * 4 + q] = o;
          }
        }
      }

      // ---- L5: 48->24, W from LDS ----
      {
        float acc[3][4];
        #pragma unroll
        for (int rr = 0; rr < 3; ++rr)
          #pragma unroll
          for (int px = 0; px < 4; ++px) acc[rr][px] = 0.f;
        float wv5[3][12];
        #pragma unroll
        for (int rr = 0; rr < 3; ++rr) {
          const float* wrow = W5r + (lt5 + 8 * rr) * 52 + 12 * q;
          #pragma unroll
          for (int i = 0; i < 12; i += 4) {
            const float4 wq = *(const float4*)(wrow + i);
            wv5[rr][i] = wq.x; wv5[rr][i+1] = wq.y; wv5[rr][i+2] = wq.z; wv5[rr][i+3] = wq.w;
          }
        }
        #pragma unroll
        for (int i = 0; i < 12; ++i) {
          const float4 tv = *(const float4*)(tab + (12 * q + i) * 4);
          #pragma unroll
          for (int rr = 0; rr < 3; ++rr) {
            const float wv = wv5[rr][i];
            acc[rr][0] += wv * tv.x; acc[rr][1] += wv * tv.y;
            acc[rr][2] += wv * tv.z; acc[rr][3] += wv * tv.w;
          }
        }
        #pragma unroll
        for (int rr = 0; rr < 3; ++rr) {
          const float s0 = quad_red(acc[rr][0]), s1 = quad_red(acc[rr][1]);
          const float s2 = quad_red(acc[rr][2]), s3 = quad_red(acc[rr][3]);
          float z = sel4f(s0, s1, s2, s3, q) + b5r[rr];
          float o = (z >= 0.f) ? z : 0.01f * z;
          if (lane < 32) tab[(lt5 + 8 * rr) * 4 + q] = o;
        }
      }

      // ---- L6 (24->12, to regs) + L7 (12->1) + delta ----
      {
        float acc[3][4];
        #pragma unroll
        for (int rr = 0; rr < 3; ++rr)
          #pragma unroll
          for (int px = 0; px < 4; ++px) acc[rr][px] = 0.f;
        #pragma unroll
        for (int i = 0; i < 6; ++i) {
          const float4 tv = *(const float4*)(tab + (6 * q + i) * 4);
          #pragma unroll
          for (int rr = 0; rr < 3; ++rr) {
            const float wv = W6r[(lt6 + 4 * rr) * 32 + 8 * q + i];
            acc[rr][0] += wv * tv.x; acc[rr][1] += wv * tv.y;
            acc[rr][2] += wv * tv.z; acc[rr][3] += wv * tv.w;
          }
        }
        float p7[4];
        #pragma unroll
        for (int px = 0; px < 4; ++px) {
          float s = 0.f;
          #pragma unroll
          for (int rr = 0; rr < 3; ++rr) {
            float z = quad_red(acc[rr][px]) + b6r[rr];
            float h = (z >= 0.f) ? z : 0.01f * z;
            s += w7r[rr] * h;
          }
          s += __shfl_xor(s, 4);
          s += __shfl_xor(s, 8);
          p7[px] = s;
        }
        if (lane < 4) {
          const bool ap = sel4i((int)act[0], (int)act[1], (int)act[2], (int)act[3], lane);
          if (ap) {
            const float pv = sel4f(p7[0], p7[1], p7[2], p7[3], lane) + B7v;
            const float xcs = sel4f(xcv[0], xcv[1], xcv[2], xcv[3], lane);
            const int rp = sel4i(rs[0], rs[1], rs[2], rs[3], lane);
            const int jp = sel4i(js[0], js[1], js[2], js[3], lane);
            const float pred = fminf(1.f, fmaxf(-1.f, pv));
            const float delta = xcs - pred;
            dpl[rp * DSTR + jp + 3] = delta;
            sumsq += delta * delta;
            if (delta <= 1.0f) {
              int bin = (int)((delta + 1.0f) * 128.0f);
              bin = bin > 255 ? 255 : (bin < 0 ? 0 : bin);
              atomicAdd(&hist[bin], 1u);
            }
          }
        }
      }
    }
    __syncthreads();
  }

  // ---- stats flush ----
  {
    float v = sumsq;
    #pragma unroll
    for (int off = 32; off; off >>= 1) v += __shfl_down(v, off);
    if (lane == 0) wred[wid] = v;
  }
  __syncthreads();
  if (tid == 0) {
    float s = 0.f;
    #pragma unroll
    for (int w = 0; w < NW; ++w) s += wred[w];
    g_sumsq[plane] = s;
  }
  if (tid < 256) {
    const unsigned c = hist[tid];
    if (c) atomicAdd(&g_hist[tid], c);
  }
}

__global__ void codec_init_kernel(unsigned* g_hist, float* g_sumsq) {
  const int t = threadIdx.x;
  if (t < 256) g_hist[t] = 0u;
  if (t < 24)  g_sumsq[t] = 0.f;
}

__global__ void codec_final_kernel(const unsigned* __restrict__ g_hist,
                                   const float* __restrict__ g_sumsq,
                                   float* __restrict__ out)
{
  __shared__ float sred[256];
  const int t = threadIdx.x;
  sred[t] = (t < 24) ? g_sumsq[t] : 0.f;
  __syncthreads();
  for (int off = 128; off; off >>= 1) {
    if (t < off) sred[t] += sred[t + off];
    __syncthreads();
  }
  const float loss = sqrtf(sred[0] / 387072.f);   // 8*3*126*128
  __syncthreads();

  const unsigned c = g_hist[t] + (t == 128 ? 2928u : 0u);  // bottom zero-row
  float ent = 0.f;
  if (c) {
    const float pr = (float)c / 360144.0f;        // 24*123*122
    ent = -pr * log2f(pr);
  }
  sred[t] = ent;
  __syncthreads();
  for (int off = 128; off; off >>= 1) {
    if (t < off) sred[t] += sred[t + off];
    __syncthreads();
  }
  if (t == 0) { out[0] = loss; out[1] = sred[0] * 0.125f; }
}

extern "C" void kernel_launch(void* const* d_in, const int* in_sizes, int n_in,
                              void* d_out, int out_size, void* d_ws, size_t ws_size,
                              hipStream_t stream) {
  const float* x  = (const float*)d_in[0];
  const float* W1 = (const float*)d_in[1];  const float* b1 = (const float*)d_in[2];
  const float* W2 = (const float*)d_in[3];  const float* b2 = (const float*)d_in[4];
  const float* W3 = (const float*)d_in[5];  const float* b3 = (const float*)d_in[6];
  const float* W4 = (const float*)d_in[7];  const float* b4 = (const float*)d_in[8];
  const float* W5 = (const float*)d_in[9];  const float* b5 = (const float*)d_in[10];
  const float* W6 = (const float*)d_in[11]; const float* b6 = (const float*)d_in[12];
  const float* W7 = (const float*)d_in[13]; const float* b7 = (const float*)d_in[14];

  unsigned* g_hist = (unsigned*)d_ws;           // 256 u32
  float* g_sumsq = (float*)d_ws + 256;          // 24 f32

  (void)hipFuncSetAttribute((const void*)codec_main_kernel,
                            hipFuncAttributeMaxDynamicSharedMemorySize, DYN_BYTES);

  codec_init_kernel<<<1, 256, 0, stream>>>(g_hist, g_sumsq);
  codec_main_kernel<<<24, 512, DYN_BYTES, stream>>>(x, W1, b1, W2, b2, W3, b3,
                                                    W4, b4, W5, b5, W6, b6, W7, b7,
                                                    g_hist, g_sumsq);
  codec_final_kernel<<<1, 256, 0, stream>>>(g_hist, g_sumsq, (float*)d_out);
}

// Round 7
// 5278.309 us; speedup vs baseline: 1.0929x; 1.0929x over previous
//
#include <hip/hip_runtime.h>
#include <math.h>

#define HDIM 128
#define NSTEP 606
#define NW 8                    // waves per block
#define DSTR 129                // dpl row stride (floats)

// dynamic-LDS carve (float indices)
#define O_DPL   0                          // 122*129 = 15738
#define O_W5    15740                      // 24*52 = 1248 (16B aligned)
#define O_W6    (O_W5 + 24*52)             // 12*32 = 384
#define O_T0    (O_W6 + 12*32)             // NW*192
#define O_TA    (O_T0 + NW*192)            // NW*192
#define O_HIST  (O_TA + NW*192)            // 256 u32
#define O_WRED  (O_HIST + 256)             // NW
#define DYN_FLOATS (O_WRED + NW)
#define DYN_BYTES  (DYN_FLOATS * 4)        // ~82.8 KB

template <int CTRL>
__device__ __forceinline__ float dpp_qp(float v) {
  // quad_perm DPP move (VALU pipe, no LDS)
  return __int_as_float(__builtin_amdgcn_mov_dpp(__float_as_int(v), CTRL, 0xf, 0xf, true));
}
__device__ __forceinline__ float quad_red(float v) {
  v += dpp_qp<0xB1>(v);   // quad_perm [1,0,3,2]  (xor 1)
  v += dpp_qp<0x4E>(v);   // quad_perm [2,3,0,1]  (xor 2)
  return v;
}
__device__ __forceinline__ float sel4f(float a0, float a1, float a2, float a3, int lane) {
  float m01 = (lane & 1) ? a1 : a0;
  float m23 = (lane & 1) ? a3 : a2;
  return (lane & 2) ? m23 : m01;
}
__device__ __forceinline__ int sel4i(int a0, int a1, int a2, int a3, int lane) {
  int m01 = (lane & 1) ? a1 : a0;
  int m23 = (lane & 1) ? a3 : a2;
  return (lane & 2) ? m23 : m01;
}

__global__ __launch_bounds__(512)
__attribute__((amdgpu_waves_per_eu(1, 2)))   // target <=2 waves/EU -> 256-VGPR budget
void codec_main_kernel(const float* __restrict__ x,
    const float* __restrict__ W1, const float* __restrict__ b1,
    const float* __restrict__ W2, const float* __restrict__ b2,
    const float* __restrict__ W3, const float* __restrict__ b3,
    const float* __restrict__ W4, const float* __restrict__ b4,
    const float* __restrict__ W5, const float* __restrict__ b5,
    const float* __restrict__ W6, const float* __restrict__ b6,
    const float* __restrict__ W7, const float* __restrict__ b7,
    unsigned* __restrict__ g_hist, float* __restrict__ g_sumsq)
{
  extern __shared__ float dyn[];
  float* dpl  = dyn + O_DPL;
  float* W5r  = dyn + O_W5;                 // [24][52]
  float* W6r  = dyn + O_W6;                 // [12][32], quarter q at col 8q
  unsigned* hist = (unsigned*)(dyn + O_HIST);
  float* wred = dyn + O_WRED;

  const int tid = threadIdx.x, wid = tid >> 6, lane = tid & 63;
  const int plane = blockIdx.x;
  const float* xp = x + (size_t)plane * (HDIM * HDIM);
  float* t0b = dyn + O_T0 + wid * 192;      // [48][4] px-packed, wave-private
  float* tab = dyn + O_TA + wid * 192;

  // ---- stage LDS weights, zero dpl/tbuf/hist/wred ----
  for (int i = tid; i < 24 * 48; i += 512) W5r[(i / 48) * 52 + (i % 48)] = W5[i];
  for (int i = tid; i < 12 * 24; i += 512) {
    int r = i / 24, k = i % 24;
    W6r[r * 32 + (k / 6) * 8 + (k % 6)] = W6[i];
  }
  for (int i = tid; i < 122 * DSTR; i += 512) dpl[i] = 0.f;
  for (int i = tid; i < NW * 384; i += 512) dyn[O_T0 + i] = 0.f;
  if (tid < 256) hist[tid] = 0u;
  if (tid < NW) wred[tid] = 0.f;

  // ---- per-lane register weights (L1-4) ----
  const int lt = lane >> 2, q = lane & 3;
  float w14[4][3][12], b14[4][3];
  {
    const float* Ws[4] = {W1, W2, W3, W4};
    const float* Bs[4] = {b1, b2, b3, b4};
    #pragma unroll
    for (int L = 0; L < 4; ++L)
      #pragma unroll
      for (int rr = 0; rr < 3; ++rr) {
        const int row = lt + 16 * rr;
        b14[L][rr] = Bs[L][row];
        #pragma unroll
        for (int kk = 0; kk < 12; ++kk) w14[L][rr][kk] = Ws[L][row * 48 + 12 * q + kk];
      }
  }
  const int lt5 = lt & 7, lt6 = lt & 3;
  float b5r[3], b6r[3], w7r[3];
  #pragma unroll
  for (int rr = 0; rr < 3; ++rr) {
    b5r[rr] = b5[lt5 + 8 * rr];
    b6r[rr] = b6[lt6 + 4 * rr];
    w7r[rr] = (lane < 16) ? W7[lt6 + 4 * rr] : 0.f;
  }
  const float B7v = b7[0];

  // ---- per-lane gather geometry ----
  const bool isx = (lane < 24) || (lane == 48);
  const bool isd = (lane >= 24 && lane < 48);
  int xro = 0, xco = 0, dro = 0, dco = 0;
  if (isx) { xro = (lane < 21) ? lane / 7 : 3; xco = (lane < 21) ? lane % 7 : (lane < 24 ? lane - 21 : 3); }
  if (isd) { const int g = lane - 24; dro = (g < 21) ? g / 7 - 3 : 0; dco = (g < 21) ? g % 7 : g - 21; }

  __syncthreads();

  float xpre[4] = {0.f, 0.f, 0.f, 0.f};
  float sumsq = 0.f;
  // initial prefetch for T=0
  #pragma unroll
  for (int p = 0; p < 4; ++p) {
    const int r = (wid & 7) + 8 * p, j = 0 - 4 * r;
    if (isx && j >= 0 && r <= 121) xpre[p] = xp[(r + xro) * HDIM + (j + xco)];
  }

  for (int T = 0; T < NSTEP; ++T) {
    const int r_lo = (T > 121) ? ((T - 118) >> 2) : 0;
    const int rbase = r_lo + ((wid - r_lo) & 7);

    int rs[4], js[4];
    bool act[4];
    float xcv[4] = {0.f, 0.f, 0.f, 0.f};
    #pragma unroll
    for (int p = 0; p < 4; ++p) {
      rs[p] = rbase + 8 * p;
      js[p] = T - 4 * rs[p];
      act[p] = (js[p] >= 0) && (rs[p] <= 121);
    }

    if (act[0]) {     // wave-uniform: any work this step?
      // ---- gather t0 (px-packed), grab xc ----
      #pragma unroll
      for (int p = 0; p < 4; ++p) {
        if (act[p]) {
          float v;
          if (isx) v = xpre[p];
          else if (isd) {
            const int drow = rs[p] + dro, dcol = js[p] + dco;
            v = (drow >= 0) ? dpl[drow * DSTR + dcol] : 0.f;
          } else v = 0.f;
          if (lane < 48) t0b[lane * 4 + p] = v;
          xcv[p] = __shfl(v, 48);
        }
      }
      // ---- prefetch x for T+1 (latency hidden under MLP) ----
      {
        const int Tn = T + 1;
        const int r_lo_n = (Tn > 121) ? ((Tn - 118) >> 2) : 0;
        const int rbase_n = r_lo_n + ((wid - r_lo_n) & 7);
        #pragma unroll
        for (int p = 0; p < 4; ++p) {
          const int rn = rbase_n + 8 * p, jn = Tn - 4 * rn;
          if (isx && jn >= 0 && rn <= 121) xpre[p] = xp[(rn + xro) * HDIM + (jn + xco)];
        }
      }

      // ---- L1-4: reg-weights, px-packed LDS activations, quad-reduce ----
      {
        const float* srcs[4] = {t0b, tab, tab, tab};
        #pragma unroll
        for (int L = 0; L < 4; ++L) {
          const float* src = srcs[L];
          float acc[3][4];
          #pragma unroll
          for (int rr = 0; rr < 3; ++rr)
            #pragma unroll
            for (int px = 0; px < 4; ++px) acc[rr][px] = 0.f;
          #pragma unroll
          for (int i = 0; i < 12; ++i) {
            const float4 tv = *(const float4*)(src + (12 * q + i) * 4);
            #pragma unroll
            for (int rr = 0; rr < 3; ++rr) {
              const float wv = w14[L][rr][i];
              acc[rr][0] += wv * tv.x; acc[rr][1] += wv * tv.y;
              acc[rr][2] += wv * tv.z; acc[rr][3] += wv * tv.w;
            }
          }
          #pragma unroll
          for (int rr = 0; rr < 3; ++rr) {
            const float s0 = quad_red(acc[rr][0]), s1 = quad_red(acc[rr][1]);
            const float s2 = quad_red(acc[rr][2]), s3 = quad_red(acc[rr][3]);
            float z = sel4f(s0, s1, s2, s3, q) + b14[L][rr];
            float o = (z >= 0.f) ? z : 0.01f * z;
            if (L == 3) o += t0b[(lt + 16 * rr) * 4 + q];
            tab[(lt + 16 * rr) * 4 + q] = o;
          }
        }
      }

      // ---- L5: 48->24, weights streamed from LDS (low reg pressure) ----
      {
        float acc[3][4];
        #pragma unroll
        for (int rr = 0; rr < 3; ++rr)
          #pragma unroll
          for (int px = 0; px < 4; ++px) acc[rr][px] = 0.f;
        #pragma unroll
        for (int ic = 0; ic < 3; ++ic) {              // 3 chunks of 4 k
          float4 wq0 = *(const float4*)(W5r + (lt5 + 0)  * 52 + 12 * q + 4 * ic);
          float4 wq1 = *(const float4*)(W5r + (lt5 + 8)  * 52 + 12 * q + 4 * ic);
          float4 wq2 = *(const float4*)(W5r + (lt5 + 16) * 52 + 12 * q + 4 * ic);
          #pragma unroll
          for (int kk = 0; kk < 4; ++kk) {
            const float4 tv = *(const float4*)(tab + (12 * q + 4 * ic + kk) * 4);
            const float w0 = (&wq0.x)[kk], w1 = (&wq1.x)[kk], w2 = (&wq2.x)[kk];
            acc[0][0] += w0 * tv.x; acc[0][1] += w0 * tv.y; acc[0][2] += w0 * tv.z; acc[0][3] += w0 * tv.w;
            acc[1][0] += w1 * tv.x; acc[1][1] += w1 * tv.y; acc[1][2] += w1 * tv.z; acc[1][3] += w1 * tv.w;
            acc[2][0] += w2 * tv.x; acc[2][1] += w2 * tv.y; acc[2][2] += w2 * tv.z; acc[2][3] += w2 * tv.w;
          }
        }
        #pragma unroll
        for (int rr = 0; rr < 3; ++rr) {
          const float s0 = quad_red(acc[rr][0]), s1 = quad_red(acc[rr][1]);
          const float s2 = quad_red(acc[rr][2]), s3 = quad_red(acc[rr][3]);
          float z = sel4f(s0, s1, s2, s3, q) + b5r[rr];
          float o = (z >= 0.f) ? z : 0.01f * z;
          if (lane < 32) tab[(lt5 + 8 * rr) * 4 + q] = o;
        }
      }

      // ---- L6 (24->12, to regs) + L7 (12->1) + delta ----
      {
        float acc[3][4];
        #pragma unroll
        for (int rr = 0; rr < 3; ++rr)
          #pragma unroll
          for (int px = 0; px < 4; ++px) acc[rr][px] = 0.f;
        #pragma unroll
        for (int i = 0; i < 6; ++i) {
          const float4 tv = *(const float4*)(tab + (6 * q + i) * 4);
          #pragma unroll
          for (int rr = 0; rr < 3; ++rr) {
            const float wv = W6r[(lt6 + 4 * rr) * 32 + 8 * q + i];
            acc[rr][0] += wv * tv.x; acc[rr][1] += wv * tv.y;
            acc[rr][2] += wv * tv.z; acc[rr][3] += wv * tv.w;
          }
        }
        float p7[4];
        #pragma unroll
        for (int px = 0; px < 4; ++px) {
          float s = 0.f;
          #pragma unroll
          for (int rr = 0; rr < 3; ++rr) {
            float z = quad_red(acc[rr][px]) + b6r[rr];
            float h = (z >= 0.f) ? z : 0.01f * z;
            s += w7r[rr] * h;
          }
          s += __shfl_xor(s, 4);
          s += __shfl_xor(s, 8);
          p7[px] = s;
        }
        if (lane < 4) {
          const bool ap = sel4i((int)act[0], (int)act[1], (int)act[2], (int)act[3], lane);
          if (ap) {
            const float pv = sel4f(p7[0], p7[1], p7[2], p7[3], lane) + B7v;
            const float xcs = sel4f(xcv[0], xcv[1], xcv[2], xcv[3], lane);
            const int rp = sel4i(rs[0], rs[1], rs[2], rs[3], lane);
            const int jp = sel4i(js[0], js[1], js[2], js[3], lane);
            const float pred = fminf(1.f, fmaxf(-1.f, pv));
            const float delta = xcs - pred;
            dpl[rp * DSTR + jp + 3] = delta;
            sumsq += delta * delta;
            if (delta <= 1.0f) {
              int bin = (int)((delta + 1.0f) * 128.0f);
              bin = bin > 255 ? 255 : (bin < 0 ? 0 : bin);
              atomicAdd(&hist[bin], 1u);
            }
          }
        }
      }
    }
    __syncthreads();
  }

  // ---- stats flush ----
  {
    float v = sumsq;
    #pragma unroll
    for (int off = 32; off; off >>= 1) v += __shfl_down(v, off);
    if (lane == 0) wred[wid] = v;
  }
  __syncthreads();
  if (tid == 0) {
    float s = 0.f;
    #pragma unroll
    for (int w = 0; w < NW; ++w) s += wred[w];
    g_sumsq[plane] = s;
  }
  if (tid < 256) {
    const unsigned c = hist[tid];
    if (c) atomicAdd(&g_hist[tid], c);
  }
}

__global__ void codec_init_kernel(unsigned* g_hist, float* g_sumsq) {
  const int t = threadIdx.x;
  if (t < 256) g_hist[t] = 0u;
  if (t < 24)  g_sumsq[t] = 0.f;
}

__global__ void codec_final_kernel(const unsigned* __restrict__ g_hist,
                                   const float* __restrict__ g_sumsq,
                                   float* __restrict__ out)
{
  __shared__ float sred[256];
  const int t = threadIdx.x;
  sred[t] = (t < 24) ? g_sumsq[t] : 0.f;
  __syncthreads();
  for (int off = 128; off; off >>= 1) {
    if (t < off) sred[t] += sred[t + off];
    __syncthreads();
  }
  const float loss = sqrtf(sred[0] / 387072.f);   // 8*3*126*128
  __syncthreads();

  const unsigned c = g_hist[t] + (t == 128 ? 2928u : 0u);  // bottom zero-row
  float ent = 0.f;
  if (c) {
    const float pr = (float)c / 360144.0f;        // 24*123*122
    ent = -pr * log2f(pr);
  }
  sred[t] = ent;
  __syncthreads();
  for (int off = 128; off; off >>= 1) {
    if (t < off) sred[t] += sred[t + off];
    __syncthreads();
  }
  if (t == 0) { out[0] = loss; out[1] = sred[0] * 0.125f; }
}

extern "C" void kernel_launch(void* const* d_in, const int* in_sizes, int n_in,
                              void* d_out, int out_size, void* d_ws, size_t ws_size,
                              hipStream_t stream) {
  const float* x  = (const float*)d_in[0];
  const float* W1 = (const float*)d_in[1];  const float* b1 = (const float*)d_in[2];
  const float* W2 = (const float*)d_in[3];  const float* b2 = (const float*)d_in[4];
  const float* W3 = (const float*)d_in[5];  const float* b3 = (const float*)d_in[6];
  const float* W4 = (const float*)d_in[7];  const float* b4 = (const float*)d_in[8];
  const float* W5 = (const float*)d_in[9];  const float* b5 = (const float*)d_in[10];
  const float* W6 = (const float*)d_in[11]; const float* b6 = (const float*)d_in[12];
  const float* W7 = (const float*)d_in[13]; const float* b7 = (const float*)d_in[14];

  unsigned* g_hist = (unsigned*)d_ws;           // 256 u32
  float* g_sumsq = (float*)d_ws + 256;          // 24 f32

  (void)hipFuncSetAttribute((const void*)codec_main_kernel,
                            hipFuncAttributeMaxDynamicSharedMemorySize, DYN_BYTES);

  codec_init_kernel<<<1, 256, 0, stream>>>(g_hist, g_sumsq);
  codec_main_kernel<<<24, 512, DYN_BYTES, stream>>>(x, W1, b1, W2, b2, W3, b3,
                                                    W4, b4, W5, b5, W6, b6, W7, b7,
                                                    g_hist, g_sumsq);
  codec_final_kernel<<<1, 256, 0, stream>>>(g_hist, g_sumsq, (float*)d_out);
}

// Round 8
// 4276.826 us; speedup vs baseline: 1.3488x; 1.2342x over previous
//
#include <hip/hip_runtime.h>
#include <math.h>

#define HDIM 128
#define NSTEP 606
#define NW 8                    // waves per block
#define DSTR 129                // dpl row stride (floats)
#define ASTR 208                // activation buffer floats per wave (padded layout)

// dynamic-LDS carve (float indices)
#define O_DPL   0                          // 122*129 = 15738
#define O_WB    15740                      // 5 layers * 64 lanes * 36 = 11520 (per-lane blobs)
#define O_W6    (O_WB + 5*64*36)           // 12*32 = 384
#define O_T0    (O_W6 + 12*32)             // NW*ASTR
#define O_TA    (O_T0 + NW*ASTR)           // NW*ASTR
#define O_HIST  (O_TA + NW*ASTR)           // 256 u32
#define O_WRED  (O_HIST + 256)             // NW
#define DYN_FLOATS (O_WRED + NW)
#define DYN_BYTES  (DYN_FLOATS * 4)        // ~125 KB

template <int CTRL>
__device__ __forceinline__ float dpp_qp(float v) {
  return __int_as_float(__builtin_amdgcn_mov_dpp(__float_as_int(v), CTRL, 0xf, 0xf, true));
}
__device__ __forceinline__ float quad_red(float v) {
  v += dpp_qp<0xB1>(v);   // quad_perm xor 1
  v += dpp_qp<0x4E>(v);   // quad_perm xor 2
  return v;
}
__device__ __forceinline__ float sel4f(float a0, float a1, float a2, float a3, int lane) {
  float m01 = (lane & 1) ? a1 : a0;
  float m23 = (lane & 1) ? a3 : a2;
  return (lane & 2) ? m23 : m01;
}
__device__ __forceinline__ int sel4i(int a0, int a1, int a2, int a3, int lane) {
  int m01 = (lane & 1) ? a1 : a0;
  int m23 = (lane & 1) ? a3 : a2;
  return (lane & 2) ? m23 : m01;
}

__global__ __launch_bounds__(512)
void codec_main_kernel(const float* __restrict__ x,
    const float* __restrict__ W1, const float* __restrict__ b1,
    const float* __restrict__ W2, const float* __restrict__ b2,
    const float* __restrict__ W3, const float* __restrict__ b3,
    const float* __restrict__ W4, const float* __restrict__ b4,
    const float* __restrict__ W5, const float* __restrict__ b5,
    const float* __restrict__ W6, const float* __restrict__ b6,
    const float* __restrict__ W7, const float* __restrict__ b7,
    unsigned* __restrict__ g_hist, float* __restrict__ g_sumsq)
{
  extern __shared__ float dyn[];
  float* dpl  = dyn + O_DPL;
  float* W6r  = dyn + O_W6;                 // [12][32], quarter q at col 8q
  unsigned* hist = (unsigned*)(dyn + O_HIST);
  float* wred = dyn + O_WRED;

  const int tid = threadIdx.x, wid = tid >> 6, lane = tid & 63;
  const int plane = blockIdx.x;
  const float* xp = x + (size_t)plane * (HDIM * HDIM);
  float* t0b = dyn + O_T0 + wid * ASTR;     // padded act layout, wave-private
  float* tab = dyn + O_TA + wid * ASTR;

  // ---- pack per-lane weight blobs: blob[(L*64+l)*36 + rr*12 + kk] ----
  for (int j = tid; j < 5 * 64; j += 512) {
    const int L = j >> 6, l = j & 63;
    const int plt = l >> 2, pq = l & 3;
    float* dst = dyn + O_WB + j * 36;
    const float* W = (L == 0) ? W1 : (L == 1) ? W2 : (L == 2) ? W3 : (L == 3) ? W4 : W5;
    for (int rr = 0; rr < 3; ++rr) {
      const int row = (L < 4) ? (plt + 16 * rr) : ((plt & 7) + 8 * rr);
      for (int kk = 0; kk < 12; ++kk)
        dst[rr * 12 + kk] = W[row * 48 + 12 * pq + kk];
    }
  }
  for (int i = tid; i < 12 * 24; i += 512) {
    int r = i / 24, k = i % 24;
    W6r[r * 32 + (k / 6) * 8 + (k % 6)] = W6[i];
  }
  for (int i = tid; i < 122 * DSTR; i += 512) dpl[i] = 0.f;
  for (int i = tid; i < NW * ASTR; i += 512) { dyn[O_T0 + i] = 0.f; dyn[O_TA + i] = 0.f; }
  if (tid < 256) hist[tid] = 0u;
  if (tid < NW) wred[tid] = 0.f;

  // ---- per-lane constants ----
  const int lt = lane >> 2, q = lane & 3;
  const int lt5 = lt & 7, lt6 = lt & 3;
  float b14[4][3], b5r[3], b6r[3], w7r[3];
  {
    const float* Bs[4] = {b1, b2, b3, b4};
    #pragma unroll
    for (int L = 0; L < 4; ++L)
      #pragma unroll
      for (int rr = 0; rr < 3; ++rr) b14[L][rr] = Bs[L][lt + 16 * rr];
  }
  #pragma unroll
  for (int rr = 0; rr < 3; ++rr) {
    b5r[rr] = b5[lt5 + 8 * rr];
    b6r[rr] = b6[lt6 + 4 * rr];
    w7r[rr] = (lane < 16) ? W7[lt6 + 4 * rr] : 0.f;
  }
  const float B7v = b7[0];
  // padded activation offsets: act_off(f) = 4f + 4*(f/12)
  int wo[3], wo5[3];
  #pragma unroll
  for (int rr = 0; rr < 3; ++rr) {
    const int f14 = lt + 16 * rr;
    wo[rr]  = 4 * f14 + 4 * (f14 / 12) + q;
    const int f5 = lt5 + 8 * rr;
    wo5[rr] = 4 * f5 + 4 * (f5 / 12) + q;
  }
  const int arb = 52 * q;                       // read base: feature 12q+i at arb+4i
  const int l6b = 24 * q + 4 * (q >> 1);        // L6 read base
  const int g_off = 4 * lane + 4 * (lane / 12); // gather write (lane<48)
  const float* wbl = dyn + O_WB + lane * 36;    // this lane's blob (layer L at +L*2304)

  // ---- per-lane gather geometry ----
  const bool isx = (lane < 24) || (lane == 48);
  const bool isd = (lane >= 24 && lane < 48);
  int xro = 0, xco = 0, dro = 0, dco = 0;
  if (isx) { xro = (lane < 21) ? lane / 7 : 3; xco = (lane < 21) ? lane % 7 : (lane < 24 ? lane - 21 : 3); }
  if (isd) { const int g = lane - 24; dro = (g < 21) ? g / 7 - 3 : 0; dco = (g < 21) ? g % 7 : g - 21; }

  __syncthreads();

  float xpre[4] = {0.f, 0.f, 0.f, 0.f};
  float sumsq = 0.f;
  #pragma unroll
  for (int p = 0; p < 4; ++p) {
    const int r = (wid & 7) + 8 * p, j = 0 - 4 * r;
    if (isx && j >= 0 && r <= 121) xpre[p] = xp[(r + xro) * HDIM + (j + xco)];
  }

  for (int T = 0; T < NSTEP; ++T) {
    const int r_lo = (T > 121) ? ((T - 118) >> 2) : 0;
    const int rbase = r_lo + ((wid - r_lo) & 7);

    int rs[4], js[4];
    bool act[4];
    float xcv[4] = {0.f, 0.f, 0.f, 0.f};
    #pragma unroll
    for (int p = 0; p < 4; ++p) {
      rs[p] = rbase + 8 * p;
      js[p] = T - 4 * rs[p];
      act[p] = (js[p] >= 0) && (rs[p] <= 121);
    }

    if (act[0]) {
      // ---- gather t0 (padded layout), grab xc ----
      #pragma unroll
      for (int p = 0; p < 4; ++p) {
        if (act[p]) {
          float v;
          if (isx) v = xpre[p];
          else if (isd) {
            const int drow = rs[p] + dro, dcol = js[p] + dco;
            v = (drow >= 0) ? dpl[drow * DSTR + dcol] : 0.f;
          } else v = 0.f;
          if (lane < 48) t0b[g_off + p] = v;
          xcv[p] = __shfl(v, 48);
        }
      }
      // ---- prefetch x for T+1 ----
      {
        const int Tn = T + 1;
        const int r_lo_n = (Tn > 121) ? ((Tn - 118) >> 2) : 0;
        const int rbase_n = r_lo_n + ((wid - r_lo_n) & 7);
        #pragma unroll
        for (int p = 0; p < 4; ++p) {
          const int rn = rbase_n + 8 * p, jn = Tn - 4 * rn;
          if (isx && jn >= 0 && rn <= 121) xpre[p] = xp[(rn + xro) * HDIM + (jn + xco)];
        }
      }

      // ---- L1-4: LDS per-lane weight blobs, quad-reduce ----
      #pragma unroll
      for (int L = 0; L < 4; ++L) {
        const float* src = (L == 0) ? t0b : tab;
        const float* wb = wbl + L * 2304;
        float acc[3][4];
        #pragma unroll
        for (int rr = 0; rr < 3; ++rr)
          #pragma unroll
          for (int px = 0; px < 4; ++px) acc[rr][px] = 0.f;
        #pragma unroll
        for (int ic = 0; ic < 3; ++ic) {
          const float4 w0 = *(const float4*)(wb + 0 * 12 + 4 * ic);
          const float4 w1 = *(const float4*)(wb + 1 * 12 + 4 * ic);
          const float4 w2 = *(const float4*)(wb + 2 * 12 + 4 * ic);
          #pragma unroll
          for (int kk = 0; kk < 4; ++kk) {
            const float4 tv = *(const float4*)(src + arb + 4 * (4 * ic + kk));
            const float f0 = (&w0.x)[kk], f1 = (&w1.x)[kk], f2 = (&w2.x)[kk];
            acc[0][0] += f0 * tv.x; acc[0][1] += f0 * tv.y; acc[0][2] += f0 * tv.z; acc[0][3] += f0 * tv.w;
            acc[1][0] += f1 * tv.x; acc[1][1] += f1 * tv.y; acc[1][2] += f1 * tv.z; acc[1][3] += f1 * tv.w;
            acc[2][0] += f2 * tv.x; acc[2][1] += f2 * tv.y; acc[2][2] += f2 * tv.z; acc[2][3] += f2 * tv.w;
          }
        }
        #pragma unroll
        for (int rr = 0; rr < 3; ++rr) {
          const float s0 = quad_red(acc[rr][0]), s1 = quad_red(acc[rr][1]);
          const float s2 = quad_red(acc[rr][2]), s3 = quad_red(acc[rr][3]);
          float z = sel4f(s0, s1, s2, s3, q) + b14[L][rr];
          float o = (z >= 0.f) ? z : 0.01f * z;
          if (L == 3) o += t0b[wo[rr]];
          tab[wo[rr]] = o;
        }
      }

      // ---- L5: 48->24, blob layer 4 ----
      {
        const float* wb = wbl + 4 * 2304;
        float acc[3][4];
        #pragma unroll
        for (int rr = 0; rr < 3; ++rr)
          #pragma unroll
          for (int px = 0; px < 4; ++px) acc[rr][px] = 0.f;
        #pragma unroll
        for (int ic = 0; ic < 3; ++ic) {
          const float4 w0 = *(const float4*)(wb + 0 * 12 + 4 * ic);
          const float4 w1 = *(const float4*)(wb + 1 * 12 + 4 * ic);
          const float4 w2 = *(const float4*)(wb + 2 * 12 + 4 * ic);
          #pragma unroll
          for (int kk = 0; kk < 4; ++kk) {
            const float4 tv = *(const float4*)(tab + arb + 4 * (4 * ic + kk));
            const float f0 = (&w0.x)[kk], f1 = (&w1.x)[kk], f2 = (&w2.x)[kk];
            acc[0][0] += f0 * tv.x; acc[0][1] += f0 * tv.y; acc[0][2] += f0 * tv.z; acc[0][3] += f0 * tv.w;
            acc[1][0] += f1 * tv.x; acc[1][1] += f1 * tv.y; acc[1][2] += f1 * tv.z; acc[1][3] += f1 * tv.w;
            acc[2][0] += f2 * tv.x; acc[2][1] += f2 * tv.y; acc[2][2] += f2 * tv.z; acc[2][3] += f2 * tv.w;
          }
        }
        #pragma unroll
        for (int rr = 0; rr < 3; ++rr) {
          const float s0 = quad_red(acc[rr][0]), s1 = quad_red(acc[rr][1]);
          const float s2 = quad_red(acc[rr][2]), s3 = quad_red(acc[rr][3]);
          float z = sel4f(s0, s1, s2, s3, q) + b5r[rr];
          float o = (z >= 0.f) ? z : 0.01f * z;
          if (lane < 32) tab[wo5[rr]] = o;
        }
      }

      // ---- L6 (24->12) + L7 (12->1) + delta ----
      {
        float acc[3][4];
        #pragma unroll
        for (int rr = 0; rr < 3; ++rr)
          #pragma unroll
          for (int px = 0; px < 4; ++px) acc[rr][px] = 0.f;
        #pragma unroll
        for (int i = 0; i < 6; ++i) {
          const float4 tv = *(const float4*)(tab + l6b + 4 * i);
          #pragma unroll
          for (int rr = 0; rr < 3; ++rr) {
            const float wv = W6r[(lt6 + 4 * rr) * 32 + 8 * q + i];
            acc[rr][0] += wv * tv.x; acc[rr][1] += wv * tv.y;
            acc[rr][2] += wv * tv.z; acc[rr][3] += wv * tv.w;
          }
        }
        float p7[4];
        #pragma unroll
        for (int px = 0; px < 4; ++px) {
          float s = 0.f;
          #pragma unroll
          for (int rr = 0; rr < 3; ++rr) {
            float z = quad_red(acc[rr][px]) + b6r[rr];
            float h = (z >= 0.f) ? z : 0.01f * z;
            s += w7r[rr] * h;
          }
          s += __shfl_xor(s, 4);
          s += __shfl_xor(s, 8);
          p7[px] = s;
        }
        if (lane < 4) {
          const bool ap = sel4i((int)act[0], (int)act[1], (int)act[2], (int)act[3], lane);
          if (ap) {
            const float pv = sel4f(p7[0], p7[1], p7[2], p7[3], lane) + B7v;
            const float xcs = sel4f(xcv[0], xcv[1], xcv[2], xcv[3], lane);
            const int rp = sel4i(rs[0], rs[1], rs[2], rs[3], lane);
            const int jp = sel4i(js[0], js[1], js[2], js[3], lane);
            const float pred = fminf(1.f, fmaxf(-1.f, pv));
            const float delta = xcs - pred;
            dpl[rp * DSTR + jp + 3] = delta;
            sumsq += delta * delta;
            if (delta <= 1.0f) {
              int bin = (int)((delta + 1.0f) * 128.0f);
              bin = bin > 255 ? 255 : (bin < 0 ? 0 : bin);
              atomicAdd(&hist[bin], 1u);
            }
          }
        }
      }
    }
    __syncthreads();
  }

  // ---- stats flush ----
  {
    float v = sumsq;
    #pragma unroll
    for (int off = 32; off; off >>= 1) v += __shfl_down(v, off);
    if (lane == 0) wred[wid] = v;
  }
  __syncthreads();
  if (tid == 0) {
    float s = 0.f;
    #pragma unroll
    for (int w = 0; w < NW; ++w) s += wred[w];
    g_sumsq[plane] = s;
  }
  if (tid < 256) {
    const unsigned c = hist[tid];
    if (c) atomicAdd(&g_hist[tid], c);
  }
}

__global__ void codec_init_kernel(unsigned* g_hist, float* g_sumsq) {
  const int t = threadIdx.x;
  if (t < 256) g_hist[t] = 0u;
  if (t < 24)  g_sumsq[t] = 0.f;
}

__global__ void codec_final_kernel(const unsigned* __restrict__ g_hist,
                                   const float* __restrict__ g_sumsq,
                                   float* __restrict__ out)
{
  __shared__ float sred[256];
  const int t = threadIdx.x;
  sred[t] = (t < 24) ? g_sumsq[t] : 0.f;
  __syncthreads();
  for (int off = 128; off; off >>= 1) {
    if (t < off) sred[t] += sred[t + off];
    __syncthreads();
  }
  const float loss = sqrtf(sred[0] / 387072.f);   // 8*3*126*128
  __syncthreads();

  const unsigned c = g_hist[t] + (t == 128 ? 2928u : 0u);  // bottom zero-row
  float ent = 0.f;
  if (c) {
    const float pr = (float)c / 360144.0f;        // 24*123*122
    ent = -pr * log2f(pr);
  }
  sred[t] = ent;
  __syncthreads();
  for (int off = 128; off; off >>= 1) {
    if (t < off) sred[t] += sred[t + off];
    __syncthreads();
  }
  if (t == 0) { out[0] = loss; out[1] = sred[0] * 0.125f; }
}

extern "C" void kernel_launch(void* const* d_in, const int* in_sizes, int n_in,
                              void* d_out, int out_size, void* d_ws, size_t ws_size,
                              hipStream_t stream) {
  const float* x  = (const float*)d_in[0];
  const float* W1 = (const float*)d_in[1];  const float* b1 = (const float*)d_in[2];
  const float* W2 = (const float*)d_in[3];  const float* b2 = (const float*)d_in[4];
  const float* W3 = (const float*)d_in[5];  const float* b3 = (const float*)d_in[6];
  const float* W4 = (const float*)d_in[7];  const float* b4 = (const float*)d_in[8];
  const float* W5 = (const float*)d_in[9];  const float* b5 = (const float*)d_in[10];
  const float* W6 = (const float*)d_in[11]; const float* b6 = (const float*)d_in[12];
  const float* W7 = (const float*)d_in[13]; const float* b7 = (const float*)d_in[14];

  unsigned* g_hist = (unsigned*)d_ws;           // 256 u32
  float* g_sumsq = (float*)d_ws + 256;          // 24 f32

  (void)hipFuncSetAttribute((const void*)codec_main_kernel,
                            hipFuncAttributeMaxDynamicSharedMemorySize, DYN_BYTES);

  codec_init_kernel<<<1, 256, 0, stream>>>(g_hist, g_sumsq);
  codec_main_kernel<<<24, 512, DYN_BYTES, stream>>>(x, W1, b1, W2, b2, W3, b3,
                                                    W4, b4, W5, b5, W6, b6, W7, b7,
                                                    g_hist, g_sumsq);
  codec_final_kernel<<<1, 256, 0, stream>>>(g_hist, g_sumsq, (float*)d_out);
}

// Round 9
// 3088.566 us; speedup vs baseline: 1.8677x; 1.3847x over previous
//
#include <hip/hip_runtime.h>
#include <math.h>

#define HDIM 128
#define NSTEP 606
#define NW 8                    // waves per block
#define DSTR 129                // dpl row stride (floats)
#define TSTRIDE 52              // per-pixel activation stride (floats)
#define ASTR (4 * TSTRIDE)      // activation floats per wave

// dynamic-LDS carve (float indices)
#define O_DPL   0                          // 122*129 = 15738
#define O_WL    15740                      // 5*48*52 = 12480 (rows padded to 52)
#define O_W6    (O_WL + 5*48*52)           // 12*28 (+pad)
#define O_T0    (O_W6 + 352)               // NW*ASTR
#define O_TA    (O_T0 + NW*ASTR)           // NW*ASTR
#define O_HIST  (O_TA + NW*ASTR)           // 256 u32
#define O_WRED  (O_HIST + 256)             // NW
#define DYN_FLOATS (O_WRED + NW)
#define DYN_BYTES  (DYN_FLOATS * 4)        // ~125.7 KB

typedef float v2f __attribute__((ext_vector_type(2)));
typedef float v4f __attribute__((ext_vector_type(4)));

__device__ __forceinline__ void pk_fma(v2f& acc, v2f a, v2f b) {
  asm("v_pk_fma_f32 %0, %1, %2, %0" : "+v"(acc) : "v"(a), "v"(b));
}
__device__ __forceinline__ v2f vlo(v4f v) { return __builtin_shufflevector(v, v, 0, 1); }
__device__ __forceinline__ v2f vhi(v4f v) { return __builtin_shufflevector(v, v, 2, 3); }
__device__ __forceinline__ float lrelu(float z) { return (z >= 0.f) ? z : 0.01f * z; }
__device__ __forceinline__ float sel4f(float a0, float a1, float a2, float a3, int lane) {
  float m01 = (lane & 1) ? a1 : a0;
  float m23 = (lane & 1) ? a3 : a2;
  return (lane & 2) ? m23 : m01;
}
__device__ __forceinline__ int sel4i(int a0, int a1, int a2, int a3, int lane) {
  int m01 = (lane & 1) ? a1 : a0;
  int m23 = (lane & 1) ? a3 : a2;
  return (lane & 2) ? m23 : m01;
}

__global__ __launch_bounds__(512)
void codec_main_kernel(const float* __restrict__ x,
    const float* __restrict__ W1, const float* __restrict__ b1,
    const float* __restrict__ W2, const float* __restrict__ b2,
    const float* __restrict__ W3, const float* __restrict__ b3,
    const float* __restrict__ W4, const float* __restrict__ b4,
    const float* __restrict__ W5, const float* __restrict__ b5,
    const float* __restrict__ W6, const float* __restrict__ b6,
    const float* __restrict__ W7, const float* __restrict__ b7,
    unsigned* __restrict__ g_hist, float* __restrict__ g_sumsq)
{
  extern __shared__ float dyn[];
  float* dpl = dyn + O_DPL;
  float* WL  = dyn + O_WL;                  // [(L*48+row)*52 + k]
  float* W6L = dyn + O_W6;                  // [row*28 + k]
  unsigned* hist = (unsigned*)(dyn + O_HIST);
  float* wred = dyn + O_WRED;

  const int tid = threadIdx.x, wid = tid >> 6, lane = tid & 63;
  const int plane = blockIdx.x;
  const float* xp = x + (size_t)plane * (HDIM * HDIM);
  float* t0b = dyn + O_T0 + wid * ASTR;     // [px][TSTRIDE], wave-private
  float* tab = dyn + O_TA + wid * ASTR;

  // ---- stage weights (rows padded to 52), zero buffers ----
  for (int i = tid; i < 4 * 48 * 48 + 24 * 48; i += 512) {
    if (i < 4 * 48 * 48) {
      const int L = i / 2304, rem = i % 2304, row = rem / 48, k = rem % 48;
      const float* W = (L == 0) ? W1 : (L == 1) ? W2 : (L == 2) ? W3 : W4;
      WL[(L * 48 + row) * TSTRIDE + k] = W[row * 48 + k];
    } else {
      const int j = i - 4 * 48 * 48, row = j / 48, k = j % 48;
      WL[(4 * 48 + row) * TSTRIDE + k] = W5[row * 48 + k];
    }
  }
  for (int i = tid; i < 12 * 24; i += 512) {
    const int row = i / 24, k = i % 24;
    W6L[row * 28 + k] = W6[i];
  }
  for (int i = tid; i < 122 * DSTR; i += 512) dpl[i] = 0.f;
  for (int i = tid; i < NW * ASTR; i += 512) { dyn[O_T0 + i] = 0.f; dyn[O_TA + i] = 0.f; }
  if (tid < 256) hist[tid] = 0u;
  if (tid < NW) wred[tid] = 0.f;

  // ---- per-lane constants ----
  const int lt = lane >> 2, q = lane & 3;   // q = pixel slot
  const int arb = q * TSTRIDE;
  float b14[4][3];
  {
    const float* Bs[4] = {b1, b2, b3, b4};
    #pragma unroll
    for (int L = 0; L < 4; ++L)
      #pragma unroll
      for (int rr = 0; rr < 3; ++rr) b14[L][rr] = Bs[L][lt + 16 * rr];
  }
  const int l5a = (lt < 12) ? lt : 0, l5b = l5a + 12;
  const float b5a = b5[l5a], b5b = b5[l5b];
  const int rl6 = (lt < 12) ? lt : lt - 12;
  const float b6v = b6[rl6];
  const float w7r = (lt < 12) ? W7[lt] : 0.f;
  const float B7v = b7[0];

  // ---- per-lane gather geometry ----
  const bool isx = (lane < 24) || (lane == 48);
  const bool isd = (lane >= 24 && lane < 48);
  int xro = 0, xco = 0, dro = 0, dco = 0;
  if (isx) { xro = (lane < 21) ? lane / 7 : 3; xco = (lane < 21) ? lane % 7 : (lane < 24 ? lane - 21 : 3); }
  if (isd) { const int g = lane - 24; dro = (g < 21) ? g / 7 - 3 : 0; dco = (g < 21) ? g % 7 : g - 21; }

  __syncthreads();

  float xpre[4] = {0.f, 0.f, 0.f, 0.f};
  float sumsq = 0.f;
  #pragma unroll
  for (int p = 0; p < 4; ++p) {
    const int r = (wid & 7) + 8 * p, j = 0 - 4 * r;
    if (isx && j >= 0 && r <= 121) xpre[p] = xp[(r + xro) * HDIM + (j + xco)];
  }

  for (int T = 0; T < NSTEP; ++T) {
    const int r_lo = (T > 121) ? ((T - 118) >> 2) : 0;
    const int rbase = r_lo + ((wid - r_lo) & 7);

    int rs[4], js[4];
    bool act[4];
    float xcv[4] = {0.f, 0.f, 0.f, 0.f};
    #pragma unroll
    for (int p = 0; p < 4; ++p) {
      rs[p] = rbase + 8 * p;
      js[p] = T - 4 * rs[p];
      act[p] = (js[p] >= 0) && (rs[p] <= 121);
    }

    if (act[0]) {
      // ---- gather t0 [px][52]: lane<48 provides feature `lane` ----
      #pragma unroll
      for (int p = 0; p < 4; ++p) {
        if (act[p]) {
          float v;
          if (isx) v = xpre[p];
          else if (isd) {
            const int drow = rs[p] + dro, dcol = js[p] + dco;
            v = (drow >= 0) ? dpl[drow * DSTR + dcol] : 0.f;
          } else v = 0.f;
          if (lane < 48) t0b[p * TSTRIDE + lane] = v;
          xcv[p] = __shfl(v, 48);
        }
      }
      // ---- prefetch x for T+1 ----
      {
        const int Tn = T + 1;
        const int r_lo_n = (Tn > 121) ? ((Tn - 118) >> 2) : 0;
        const int rbase_n = r_lo_n + ((wid - r_lo_n) & 7);
        #pragma unroll
        for (int p = 0; p < 4; ++p) {
          const int rn = rbase_n + 8 * p, jn = Tn - 4 * rn;
          if (isx && jn >= 0 && rn <= 121) xpre[p] = xp[(rn + xro) * HDIM + (jn + xco)];
        }
      }

      // ---- L1-4: 48->48, lane = (out-group lt, px q), full-48 dots, pk_fma ----
      #pragma unroll
      for (int L = 0; L < 4; ++L) {
        const float* src = (L == 0) ? t0b : tab;
        const float* w0p = WL + (L * 48 + lt)      * TSTRIDE;
        const float* w1p = WL + (L * 48 + lt + 16) * TSTRIDE;
        const float* w2p = WL + (L * 48 + lt + 32) * TSTRIDE;
        v2f a0 = {0.f, 0.f}, a1 = {0.f, 0.f}, a2 = {0.f, 0.f};
        #pragma unroll
        for (int ic = 0; ic < 12; ++ic) {
          const v4f tv = *(const v4f*)(src + arb + 4 * ic);
          const v4f w0 = *(const v4f*)(w0p + 4 * ic);
          const v4f w1 = *(const v4f*)(w1p + 4 * ic);
          const v4f w2 = *(const v4f*)(w2p + 4 * ic);
          pk_fma(a0, vlo(w0), vlo(tv)); pk_fma(a0, vhi(w0), vhi(tv));
          pk_fma(a1, vlo(w1), vlo(tv)); pk_fma(a1, vhi(w1), vhi(tv));
          pk_fma(a2, vlo(w2), vlo(tv)); pk_fma(a2, vhi(w2), vhi(tv));
        }
        float o0 = lrelu(a0.x + a0.y + b14[L][0]);
        float o1 = lrelu(a1.x + a1.y + b14[L][1]);
        float o2 = lrelu(a2.x + a2.y + b14[L][2]);
        if (L == 3) {
          o0 += t0b[arb + lt];
          o1 += t0b[arb + lt + 16];
          o2 += t0b[arb + lt + 32];
        }
        tab[arb + lt]      = o0;
        tab[arb + lt + 16] = o1;
        tab[arb + lt + 32] = o2;
      }

      // ---- L5: 48->24, lanes lt<12 do rows lt, lt+12 ----
      if (lt < 12) {
        const float* w0p = WL + (4 * 48 + l5a) * TSTRIDE;
        const float* w1p = WL + (4 * 48 + l5b) * TSTRIDE;
        v2f a0 = {0.f, 0.f}, a1 = {0.f, 0.f};
        #pragma unroll
        for (int ic = 0; ic < 12; ++ic) {
          const v4f tv = *(const v4f*)(tab + arb + 4 * ic);
          const v4f w0 = *(const v4f*)(w0p + 4 * ic);
          const v4f w1 = *(const v4f*)(w1p + 4 * ic);
          pk_fma(a0, vlo(w0), vlo(tv)); pk_fma(a0, vhi(w0), vhi(tv));
          pk_fma(a1, vlo(w1), vlo(tv)); pk_fma(a1, vhi(w1), vhi(tv));
        }
        tab[arb + l5a] = lrelu(a0.x + a0.y + b5a);
        tab[arb + l5b] = lrelu(a1.x + a1.y + b5b);
      }

      // ---- L6: 24->12 (row rl6) + L7 via shfl_xor over lt bits ----
      {
        const float* wp = W6L + rl6 * 28;
        v2f a6 = {0.f, 0.f};
        #pragma unroll
        for (int ic = 0; ic < 6; ++ic) {
          const v4f tv = *(const v4f*)(tab + arb + 4 * ic);
          const v4f w0 = *(const v4f*)(wp + 4 * ic);
          pk_fma(a6, vlo(w0), vlo(tv)); pk_fma(a6, vhi(w0), vhi(tv));
        }
        const float h6 = lrelu(a6.x + a6.y + b6v);
        float s = w7r * h6;                  // 0 for lt>=12
        s += __shfl_xor(s, 4);
        s += __shfl_xor(s, 8);
        s += __shfl_xor(s, 16);
        s += __shfl_xor(s, 32);
        if (lane < 4) {
          const bool ap = sel4i((int)act[0], (int)act[1], (int)act[2], (int)act[3], lane);
          if (ap) {
            const float pv = s + B7v;
            const float xcs = sel4f(xcv[0], xcv[1], xcv[2], xcv[3], lane);
            const int rp = sel4i(rs[0], rs[1], rs[2], rs[3], lane);
            const int jp = sel4i(js[0], js[1], js[2], js[3], lane);
            const float pred = fminf(1.f, fmaxf(-1.f, pv));
            const float delta = xcs - pred;
            dpl[rp * DSTR + jp + 3] = delta;
            sumsq += delta * delta;
            if (delta <= 1.0f) {
              int bin = (int)((delta + 1.0f) * 128.0f);
              bin = bin > 255 ? 255 : (bin < 0 ? 0 : bin);
              atomicAdd(&hist[bin], 1u);
            }
          }
        }
      }
    }
    __syncthreads();
  }

  // ---- stats flush ----
  {
    float v = sumsq;
    #pragma unroll
    for (int off = 32; off; off >>= 1) v += __shfl_down(v, off);
    if (lane == 0) wred[wid] = v;
  }
  __syncthreads();
  if (tid == 0) {
    float s = 0.f;
    #pragma unroll
    for (int w = 0; w < NW; ++w) s += wred[w];
    g_sumsq[plane] = s;
  }
  if (tid < 256) {
    const unsigned c = hist[tid];
    if (c) atomicAdd(&g_hist[tid], c);
  }
}

__global__ void codec_init_kernel(unsigned* g_hist, float* g_sumsq) {
  const int t = threadIdx.x;
  if (t < 256) g_hist[t] = 0u;
  if (t < 24)  g_sumsq[t] = 0.f;
}

__global__ void codec_final_kernel(const unsigned* __restrict__ g_hist,
                                   const float* __restrict__ g_sumsq,
                                   float* __restrict__ out)
{
  __shared__ float sred[256];
  const int t = threadIdx.x;
  sred[t] = (t < 24) ? g_sumsq[t] : 0.f;
  __syncthreads();
  for (int off = 128; off; off >>= 1) {
    if (t < off) sred[t] += sred[t + off];
    __syncthreads();
  }
  const float loss = sqrtf(sred[0] / 387072.f);   // 8*3*126*128
  __syncthreads();

  const unsigned c = g_hist[t] + (t == 128 ? 2928u : 0u);  // bottom zero-row
  float ent = 0.f;
  if (c) {
    const float pr = (float)c / 360144.0f;        // 24*123*122
    ent = -pr * log2f(pr);
  }
  sred[t] = ent;
  __syncthreads();
  for (int off = 128; off; off >>= 1) {
    if (t < off) sred[t] += sred[t + off];
    __syncthreads();
  }
  if (t == 0) { out[0] = loss; out[1] = sred[0] * 0.125f; }
}

extern "C" void kernel_launch(void* const* d_in, const int* in_sizes, int n_in,
                              void* d_out, int out_size, void* d_ws, size_t ws_size,
                              hipStream_t stream) {
  const float* x  = (const float*)d_in[0];
  const float* W1 = (const float*)d_in[1];  const float* b1 = (const float*)d_in[2];
  const float* W2 = (const float*)d_in[3];  const float* b2 = (const float*)d_in[4];
  const float* W3 = (const float*)d_in[5];  const float* b3 = (const float*)d_in[6];
  const float* W4 = (const float*)d_in[7];  const float* b4 = (const float*)d_in[8];
  const float* W5 = (const float*)d_in[9];  const float* b5 = (const float*)d_in[10];
  const float* W6 = (const float*)d_in[11]; const float* b6 = (const float*)d_in[12];
  const float* W7 = (const float*)d_in[13]; const float* b7 = (const float*)d_in[14];

  unsigned* g_hist = (unsigned*)d_ws;           // 256 u32
  float* g_sumsq = (float*)d_ws + 256;          // 24 f32

  (void)hipFuncSetAttribute((const void*)codec_main_kernel,
                            hipFuncAttributeMaxDynamicSharedMemorySize, DYN_BYTES);

  codec_init_kernel<<<1, 256, 0, stream>>>(g_hist, g_sumsq);
  codec_main_kernel<<<24, 512, DYN_BYTES, stream>>>(x, W1, b1, W2, b2, W3, b3,
                                                    W4, b4, W5, b5, W6, b6, W7, b7,
                                                    g_hist, g_sumsq);
  codec_final_kernel<<<1, 256, 0, stream>>>(g_hist, g_sumsq, (float*)d_out);
}